// Round 1
// baseline (34.998 us; speedup 1.0000x reference)
//
#include <hip/hip_runtime.h>
#include <math.h>

#define NH 4    // heads
#define DH 8    // head dim
#define NF 64   // F
#define NT 12   // T
#define NB 2    // batch

__device__ __forceinline__ float gelu_f(float x) {
    // exact gelu: x * 0.5 * (1 + erf(x / sqrt(2)))
    return 0.5f * x * (1.0f + erff(x * 0.70710678118654752440f));
}

// One wave (64 lanes) per (b,n) row; lane = f.
// Computes sqT[(b*NH+h)*N + n] and skT[...] (transposed layout for kernel C).
__global__ __launch_bounds__(256) void qk_kernel(
    const float* __restrict__ x, const float* __restrict__ w1,
    const float* __restrict__ W2, const float* __restrict__ a,
    float* __restrict__ sqT, float* __restrict__ skT, int N)
{
    __shared__ float Wq[NF][NH + 1];
    __shared__ float Wk[NF][NH + 1];
    const int t = threadIdx.x;

    // Fold W2 (64x32) with aq/ak (8 each) -> Wq/Wk (64x4), once per block.
    {
        int f = t >> 2, h = t & 3;
        float accq = 0.f, acck = 0.f;
        #pragma unroll
        for (int k = 0; k < DH; ++k) {
            float w = W2[f * (NH * DH) + h * DH + k];
            accq += w * a[k];
            acck += w * a[DH + k];
        }
        Wq[f][h] = accq;
        Wk[f][h] = acck;
    }
    __syncthreads();

    float w1r[NT];
    #pragma unroll
    for (int i = 0; i < NT; ++i) w1r[i] = w1[i];

    const int wave = t >> 6;
    const int lane = t & 63;                      // = f
    const long long row = (long long)blockIdx.x * 4 + wave;   // in [0, NB*N)
    if (row >= (long long)NB * N) return;

    const float* xr = x + row * (NF * NT) + (long long)lane * NT;
    float4 v0 = *(const float4*)(xr);
    float4 v1 = *(const float4*)(xr + 4);
    float4 v2 = *(const float4*)(xr + 8);
    float dot = v0.x*w1r[0] + v0.y*w1r[1] + v0.z*w1r[2]  + v0.w*w1r[3]
              + v1.x*w1r[4] + v1.y*w1r[5] + v1.z*w1r[6]  + v1.w*w1r[7]
              + v2.x*w1r[8] + v2.y*w1r[9] + v2.z*w1r[10] + v2.w*w1r[11];
    float q = gelu_f(dot);

    float acc[8];
    #pragma unroll
    for (int h = 0; h < NH; ++h) {
        acc[h]     = q * Wq[lane][h];
        acc[4 + h] = q * Wk[lane][h];
    }
    #pragma unroll
    for (int ofs = 32; ofs > 0; ofs >>= 1) {
        #pragma unroll
        for (int i = 0; i < 8; ++i)
            acc[i] += __shfl_xor(acc[i], ofs, 64);
    }
    if (lane < 8) {
        int h   = lane & 3;
        int isK = lane >> 2;
        int b   = (int)(row / N);
        int n   = (int)(row % N);
        float* dst = isK ? skT : sqT;
        dst[((long long)b * NH + h) * N + n] = acc[lane];
    }
}

// One thread per (i, 4 consecutive j); loops the 8 (b,h) pairs so each adj
// float4 is fetched from HBM once and reused 8x from registers.
__global__ __launch_bounds__(256) void score_kernel(
    const float* __restrict__ adj, const float* __restrict__ sqT,
    const float* __restrict__ skT, const float* __restrict__ a,
    float* __restrict__ out, int N)
{
    const float aadj = a[2 * DH];
    const int nq = N >> 2;                         // j-quads per row
    long long tid = (long long)blockIdx.x * blockDim.x + threadIdx.x;
    if (tid >= (long long)N * nq) return;
    const int i  = (int)(tid / nq);
    const int j0 = (int)(tid % nq) << 2;

    float4 adj4 = *(const float4*)(adj + (long long)i * N + j0);
    const float a0 = adj4.x * aadj;
    const float a1 = adj4.y * aadj;
    const float a2 = adj4.z * aadj;
    const float a3 = adj4.w * aadj;

    #pragma unroll
    for (int bh = 0; bh < NB * NH; ++bh) {
        const float sq = sqT[(long long)bh * N + i];
        float4 sk4 = *(const float4*)(skT + (long long)bh * N + j0);
        float4 o;
        o.x = gelu_f(sq + sk4.x + a0);
        o.y = gelu_f(sq + sk4.y + a1);
        o.z = gelu_f(sq + sk4.z + a2);
        o.w = gelu_f(sq + sk4.w + a3);
        *(float4*)(out + ((long long)bh * N + i) * N + j0) = o;
    }
}

extern "C" void kernel_launch(void* const* d_in, const int* in_sizes, int n_in,
                              void* d_out, int out_size, void* d_ws, size_t ws_size,
                              hipStream_t stream)
{
    const float* x   = (const float*)d_in[0];
    const float* adj = (const float*)d_in[1];
    const float* w1  = (const float*)d_in[2];
    const float* W2  = (const float*)d_in[3];
    const float* a   = (const float*)d_in[4];
    float* out = (float*)d_out;

    // N from adj (N*N elements); B fixed at 2 per reference setup.
    int N = 1;
    while ((long long)(N + 1) * (N + 1) <= (long long)in_sizes[1]) ++N;

    float* sqT = (float*)d_ws;                 // NB*NH*N floats
    float* skT = sqT + (size_t)NB * NH * N;    // NB*NH*N floats

    const int rows = NB * N;                   // one wave per row, 4 waves/block
    qk_kernel<<<(rows + 3) / 4, 256, 0, stream>>>(x, w1, W2, a, sqT, skT, N);

    const long long total = (long long)N * (N >> 2);
    score_kernel<<<(int)((total + 255) / 256), 256, 0, stream>>>(adj, sqT, skT, a, out, N);
}